// Round 4
// baseline (184470.764 us; speedup 1.0000x reference)
//
#include <hip/hip_runtime.h>
#include <math.h>

#define BATCH 128
#define TDEC  550
#define TENC  500
#define EDIM  512
#define VOC   31
#define NBLK  256
#define NTHR  512

typedef float f32x4 __attribute__((ext_vector_type(4)));

// ---------------- workspace layout (float offsets) ----------------
#define OFF_WA   0u                          // [2048][1024] cols 0..511 = M (s-part), 512..1023 = w_hh0
#define OFF_WB   (OFF_WA + 2097152u)         // [2048][1024] cols 0..511 = w_ih1, 512..1023 = w_hh1
#define OFF_GM   (OFF_WB + 2097152u)         // [512][1024]  cols 0..511 = w_o2c[:, :512], 512.. = M2
#define OFF_E2G  (OFF_GM + 524288u)          // [31][2048]
#define OFF_BA   (OFF_E2G + 63488u)          // [2048]
#define OFF_BB   (OFF_BA + 2048u)            // [2048]
#define OFF_BG   (OFF_BB + 2048u)            // [512]
#define OFF_ST   (OFF_BG + 512u)             // s~ [512][128]
#define OFF_H0T0 (OFF_ST   + 65536u)
#define OFF_H0T1 (OFF_H0T0 + 65536u)
#define OFF_H1T0 (OFF_H0T1 + 65536u)
#define OFF_H1T1 (OFF_H1T0 + 65536u)
#define OFF_C0T  (OFF_H1T1 + 65536u)
#define OFF_C1T  (OFF_C0T  + 65536u)
#define OFF_P    (OFF_C1T  + 65536u)         // exp(e) [128][512] (500 used)
#define OFF_PL   (OFF_P    + 65536u)         // l partials [128][2]
#define OFF_PS   (OFF_PL   + 256u)           // s partials [128][2][512]
#define OFF_LB   (OFF_PS   + 131072u)        // logits dbl-buf [2][128][32]
#define OFF_BAR  (OFF_LB   + 8192u)          // barrier cells (1024 u32)
#define OFF_WKT  (OFF_BAR  + 1024u)          // wkT [512 e][512 d]
#define OFF_H1BK (OFF_WKT  + 262144u)        // h1 in [b][k] layout [128][512]

// ---------------- init kernel 1: copies / biases / zeros / wkT ----------------
__global__ void initCopy(const float* __restrict__ w_hh0, const float* __restrict__ w_ih1,
                         const float* __restrict__ w_hh1, const float* __restrict__ w_o2c,
                         const float* __restrict__ b_ih0, const float* __restrict__ b_hh0,
                         const float* __restrict__ b_ih1, const float* __restrict__ b_hh1,
                         const float* __restrict__ b_o2c, const float* __restrict__ wk,
                         float* __restrict__ ws)
{
  const unsigned n0 = 2048u*512u;      // WA right (w_hh0)
  const unsigned n1 = 2048u*512u;      // WB left  (w_ih1)
  const unsigned n2 = 2048u*512u;      // WB right (w_hh1)
  const unsigned n3 = 512u*512u;       // GM left
  const unsigned nz = 7u*65536u;       // ST,H0T0,H0T1,H1T0,H1T1,C0T,C1T
  const unsigned nw = 262144u;         // wkT
  const unsigned NT = n0+n1+n2+n3 + 2048u+2048u+512u + nz + 8192u + 1024u + nw;
  for (unsigned i = blockIdx.x*blockDim.x + threadIdx.x; i < NT; i += gridDim.x*blockDim.x) {
    unsigned j = i;
    if (j < n0) { unsigned r = j>>9, k = j&511u;
      ws[OFF_WA + r*1024u + 512u + k] = w_hh0[j]; continue; }
    j -= n0;
    if (j < n1) { unsigned r = j>>9, k = j&511u;
      ws[OFF_WB + r*1024u + k] = w_ih1[j]; continue; }
    j -= n1;
    if (j < n2) { unsigned r = j>>9, k = j&511u;
      ws[OFF_WB + r*1024u + 512u + k] = w_hh1[j]; continue; }
    j -= n2;
    if (j < n3) { unsigned r = j>>9, k = j&511u;
      ws[OFF_GM + r*1024u + k] = w_o2c[r*1024u + k]; continue; }
    j -= n3;
    if (j < 2048u) { ws[OFF_BA + j] = b_ih0[j] + b_hh0[j]; continue; }
    j -= 2048u;
    if (j < 2048u) { ws[OFF_BB + j] = b_ih1[j] + b_hh1[j]; continue; }
    j -= 2048u;
    if (j < 512u)  { ws[OFF_BG + j] = b_o2c[j]; continue; }
    j -= 512u;
    if (j < nz)    { ws[OFF_ST + j] = 0.f; continue; }
    j -= nz;
    if (j < 8192u) {
      unsigned buf = j>>12, v = j & 31u;
      ws[OFF_LB + j] = (buf==1u && v==0u) ? 1e9f : 0.f;   // argmax -> SOS(=0) at t=0
      continue; }
    j -= 8192u;
    if (j < 1024u) { ((unsigned*)(ws + OFF_BAR))[j] = 0u; continue; }
    j -= 1024u;
    { unsigned e = j>>9, d = j&511u;
      ws[OFF_WKT + j] = wk[d*512u + e]; }
  }
}

// ---------------- init kernel 2: folded weight GEMMs ----------------
__global__ void initGemm(const float* __restrict__ w_ih0, const float* __restrict__ w_o2c,
                         const float* __restrict__ wvm, const float* __restrict__ emb,
                         float* __restrict__ ws)
{
  const unsigned n0 = 2048u*512u;   // M  -> WA left
  const unsigned n1 = 512u*512u;    // M2 -> GM right
  const unsigned n2 = 31u*2048u;    // E2G
  const unsigned NT = n0+n1+n2;
  for (unsigned i = blockIdx.x*blockDim.x + threadIdx.x; i < NT; i += gridDim.x*blockDim.x) {
    if (i < n0) {
      unsigned r = i>>9, d = i&511u;
      const float* a = w_ih0 + (size_t)r*1024u + 512u;
      const float* b = wvm + (size_t)d*512u;
      float s = 0.f;
      for (int k = 0; k < 512; ++k) s = fmaf(a[k], b[k], s);
      ws[OFF_WA + r*1024u + d] = s;
    } else if (i < n0+n1) {
      unsigned j = i - n0; unsigned r = j>>9, d = j&511u;
      const float* a = w_o2c + (size_t)r*1024u + 512u;
      const float* b = wvm + (size_t)d*512u;
      float s = 0.f;
      for (int k = 0; k < 512; ++k) s = fmaf(a[k], b[k], s);
      ws[OFF_GM + r*1024u + 512u + d] = s;
    } else {
      unsigned j = i - n0 - n1; unsigned v = j>>11, g = j&2047u;
      const float* a = emb + (size_t)v*512u;
      const float* b = w_ih0 + (size_t)g*1024u;
      float s = 0.f;
      for (int k = 0; k < 512; ++k) s = fmaf(a[k], b[k], s);
      ws[OFF_E2G + v*2048u + g] = s;
    }
  }
}

// ---------------- hierarchical grid barrier ----------------
__device__ __forceinline__ void gridbar(float* ws, unsigned tgt)
{
  unsigned* base = (unsigned*)(ws + OFF_BAR);
  __syncthreads();
  if (threadIdx.x == 0) {
    const int g = blockIdx.x >> 5;                  // 8 groups of 32 blocks
    unsigned* cnt  = base + g*32;
    unsigned* root = base + 256;
    unsigned* gens = base + 512;
    unsigned old = __hip_atomic_fetch_add(cnt, 1u, __ATOMIC_ACQ_REL, __HIP_MEMORY_SCOPE_AGENT);
    if (old == tgt*32u - 1u) {
      unsigned old2 = __hip_atomic_fetch_add(root, 1u, __ATOMIC_ACQ_REL, __HIP_MEMORY_SCOPE_AGENT);
      if (old2 == tgt*8u - 1u) {
        #pragma unroll
        for (int gg = 0; gg < 8; ++gg)
          __hip_atomic_fetch_add(gens + gg*32, 1u, __ATOMIC_RELEASE, __HIP_MEMORY_SCOPE_AGENT);
      }
    }
    unsigned* mygen = gens + g*32;
    while (__hip_atomic_load(mygen, __ATOMIC_ACQUIRE, __HIP_MEMORY_SCOPE_AGENT) < tgt)
      __builtin_amdgcn_s_sleep(2);
  }
  __syncthreads();
}

__device__ __forceinline__ float sigm(float x) { return 1.f/(1.f + expf(-x)); }

// ---------------- main persistent kernel ----------------
__launch_bounds__(NTHR)
__global__ void speller_main(const float* __restrict__ enc, const float* __restrict__ emb,
                             const float* __restrict__ wk,  const float* __restrict__ bcp,
                             float* __restrict__ ws, float* __restrict__ out)
{
  __shared__ __align__(16) float smem[15616];
  __shared__ int symL[128];
  const int tid = threadIdx.x;
  const int blk = blockIdx.x;
  unsigned bstep = 0;

  float* rawout  = out;                                   // [128][550][31]
  float* attnout = out + (size_t)BATCH*TDEC*VOC;          // [128][550][500]

  for (int t = 0; t < TDEC; ++t) {
    const int p = t & 1;
    float*       h0_cur  = ws + (p ? OFF_H0T1 : OFF_H0T0);
    const float* h0_prev = ws + (p ? OFF_H0T0 : OFF_H0T1);
    float*       h1_cur  = ws + (p ? OFF_H1T1 : OFF_H1T0);
    const float* h1_prev = ws + (p ? OFF_H1T0 : OFF_H1T1);

    // ========== Phase A : argmax feedback + LSTM0 (block owns j0=blk*2) ==========
    {
      const float* Lb = ws + OFF_LB + (size_t)(p^1)*4096u;
      if (blk < 16) {
        if (t > 0) {
          for (int i = tid; i < 248; i += NTHR) {
            int bl = i / 31, v = i - bl*31;
            int bb = blk*8 + bl;
            __builtin_nontemporal_store(Lb[bb*32 + v] + bcp[v],
                rawout + ((size_t)bb*TDEC + (t-1))*VOC + v);
          }
        }
      } else if (blk == 16) {
        float* Lz = ws + OFF_LB + (size_t)p*4096u;
        for (int i = tid; i < 4096; i += NTHR) Lz[i] = 0.f;
      }
      if (tid < 128) {
        float best = -3.4e38f; int sy = 0;
        for (int v = 0; v < VOC; ++v) {
          float f = Lb[tid*32 + v] + bcp[v];
          if (f > best) { best = f; sy = v; }
        }
        symL[tid] = sy;
      }
      const int b  = tid & 127;
      const int kg = tid >> 7;
      const int j0 = blk*2;
      const float* xb = ((kg < 2) ? (ws + OFF_ST + (size_t)kg*256u*128u)
                                  : (h0_prev + (size_t)(kg-2)*256u*128u)) + b;
      const float* wr[8];
      #pragma unroll
      for (int r = 0; r < 8; ++r) {
        int gi = r >> 1, jl = r & 1;
        wr[r] = ws + OFF_WA + (size_t)(gi*512 + j0 + jl)*1024u + kg*256;
      }
      float acc[8] = {0,0,0,0,0,0,0,0};
      for (int k = 0; k < 256; ++k) {
        float xv = xb[(size_t)k*128u];
        #pragma unroll
        for (int r = 0; r < 8; ++r) acc[r] = fmaf(xv, wr[r][k], acc[r]);
      }
      float* lacc = smem;
      __syncthreads();
      #pragma unroll
      for (int r = 0; r < 8; ++r) lacc[(kg*128 + b)*9 + r] = acc[r];
      __syncthreads();
      if (tid < 256) {
        const int bb = tid & 127, jl = tid >> 7;
        const int j = j0 + jl;
        float gv[4];
        #pragma unroll
        for (int gi = 0; gi < 4; ++gi) {
          float s = 0.f;
          #pragma unroll
          for (int kg2 = 0; kg2 < 4; ++kg2) s += lacc[(kg2*128 + bb)*9 + gi*2 + jl];
          s += (ws + OFF_E2G)[(size_t)symL[bb]*2048u + gi*512 + j];
          s += (ws + OFF_BA)[gi*512 + j];
          gv[gi] = s;
        }
        float ig = sigm(gv[0]), fg = sigm(gv[1]);
        float gg = tanhf(gv[2]), og = sigm(gv[3]);
        float cold = (ws + OFF_C0T)[(size_t)j*128 + bb];
        float cnew = fg*cold + ig*gg;
        (ws + OFF_C0T)[(size_t)j*128 + bb] = cnew;
        h0_cur[(size_t)j*128 + bb] = og*tanhf(cnew);
      }
    }
    gridbar(ws, ++bstep);

    // ========== Phase B : LSTM1 (also writes h1bk transposed copy) ==========
    {
      const int b  = tid & 127;
      const int kg = tid >> 7;
      const int j0 = blk*2;
      const float* xb = ((kg < 2) ? (h0_cur + (size_t)kg*256u*128u)
                                  : (h1_prev + (size_t)(kg-2)*256u*128u)) + b;
      const float* wr[8];
      #pragma unroll
      for (int r = 0; r < 8; ++r) {
        int gi = r >> 1, jl = r & 1;
        wr[r] = ws + OFF_WB + (size_t)(gi*512 + j0 + jl)*1024u + kg*256;
      }
      float acc[8] = {0,0,0,0,0,0,0,0};
      for (int k = 0; k < 256; ++k) {
        float xv = xb[(size_t)k*128u];
        #pragma unroll
        for (int r = 0; r < 8; ++r) acc[r] = fmaf(xv, wr[r][k], acc[r]);
      }
      float* lacc = smem;
      __syncthreads();
      #pragma unroll
      for (int r = 0; r < 8; ++r) lacc[(kg*128 + b)*9 + r] = acc[r];
      __syncthreads();
      if (tid < 256) {
        const int bb = tid & 127, jl = tid >> 7;
        const int j = j0 + jl;
        float gv[4];
        #pragma unroll
        for (int gi = 0; gi < 4; ++gi) {
          float s = 0.f;
          #pragma unroll
          for (int kg2 = 0; kg2 < 4; ++kg2) s += lacc[(kg2*128 + bb)*9 + gi*2 + jl];
          s += (ws + OFF_BB)[gi*512 + j];
          gv[gi] = s;
        }
        float ig = sigm(gv[0]), fg = sigm(gv[1]);
        float gg = tanhf(gv[2]), og = sigm(gv[3]);
        float cold = (ws + OFF_C1T)[(size_t)j*128 + bb];
        float cnew = fg*cold + ig*gg;
        (ws + OFF_C1T)[(size_t)j*128 + bb] = cnew;
        float hval = og*tanhf(cnew);
        h1_cur[(size_t)j*128 + bb] = hval;
        (ws + OFF_H1BK)[(size_t)bb*512u + j] = hval;   // transposed copy for C/D
      }
    }
    gridbar(ws, ++bstep);

    // ========== Phase C : q + pipelined attention (block=(b,tau)) ==========
    {
      const int b = blk >> 1, tau = blk & 1;
      const int tbase = tau*250;
      float* tile = smem;            // [25][520] = 13000
      float* qL   = smem + 13000;    // 512
      float* pL   = smem + 13520;    // 32
      float* sred = smem + 13568;    // [4][512]
      float* h1L  = sred;            // alias (used before sred)

      if (tid < 128) {
        float4 h = *(const float4*)(ws + OFF_H1BK + (size_t)b*512u + tid*4);
        *(float4*)(h1L + tid*4) = h;
      }
      __syncthreads();
      // q[d] = sum_e wkT[e][d]*h1[e], 4-way e-split
      {
        const int eg = tid >> 7, dqq = (tid & 127)*4;
        const int e0 = eg*128;
        float4 qa = {0.f,0.f,0.f,0.f};
        const float* wkt = ws + OFF_WKT;
        for (int e = 0; e < 128; ++e) {
          float hv = h1L[e0 + e];
          float4 wv4 = *(const float4*)(wkt + (size_t)(e0+e)*512u + dqq);
          qa.x = fmaf(hv, wv4.x, qa.x); qa.y = fmaf(hv, wv4.y, qa.y);
          qa.z = fmaf(hv, wv4.z, qa.z); qa.w = fmaf(hv, wv4.w, qa.w);
        }
        *(float4*)(tile + eg*512 + dqq) = qa;   // tile as scratch
      }
      __syncthreads();
      if (tid < 128) {
        int dqq = tid*4;
        float4 a0 = *(float4*)(tile + dqq);
        float4 a1 = *(float4*)(tile + 512 + dqq);
        float4 a2 = *(float4*)(tile + 1024 + dqq);
        float4 a3 = *(float4*)(tile + 1536 + dqq);
        float4 q4;
        q4.x = a0.x+a1.x+a2.x+a3.x; q4.y = a0.y+a1.y+a2.y+a3.y;
        q4.z = a0.z+a1.z+a2.z+a3.z; q4.w = a0.w+a1.w+a2.w+a3.w;
        *(float4*)(qL + dqq) = q4;
      }
      // prologue: prefetch tile 0
      float4 rv[7];
      const float* encb = enc + ((size_t)b*TENC + tbase)*EDIM;
      #pragma unroll
      for (int jj = 0; jj < 7; ++jj) {
        int i2 = tid + jj*512;
        if (i2 < 3200) rv[jj] = *(const float4*)(encb + (size_t)i2*4u);
      }
      float sa0=0.f, sa1=0.f, sa2=0.f, sa3=0.f;
      float ltot = 0.f;
      const int rr = tid >> 3, cc = tid & 7;
      const int qr = tid >> 7, dqq = (tid & 127)*4;
      const int rs = qr*6 + (qr>0 ? 1 : 0);
      const int rcnt = (qr==0) ? 7 : 6;
      __syncthreads();   // qL ready, tile scratch free
      for (int ti = 0; ti < 10; ++ti) {
        #pragma unroll
        for (int jj = 0; jj < 7; ++jj) {
          int i2 = tid + jj*512;
          if (i2 < 3200) { int r = i2 >> 7, c = i2 & 127; *(float4*)(tile + r*520 + c*4) = rv[jj]; }
        }
        __syncthreads();
        if (ti < 9) {      // prefetch next tile (overlaps compute)
          const float* encn = encb + (size_t)(ti+1)*25u*EDIM;
          #pragma unroll
          for (int jj = 0; jj < 7; ++jj) {
            int i2 = tid + jj*512;
            if (i2 < 3200) rv[jj] = *(const float4*)(encn + (size_t)i2*4u);
          }
        }
        if (rr < 25) {
          float a = 0.f;
          const float* tr = tile + rr*520;
          #pragma unroll
          for (int i = 0; i < 16; ++i) {
            int d = i*32 + cc*4;
            float4 tv = *(const float4*)(tr + d);
            float4 qv = *(const float4*)(qL + d);
            a = fmaf(tv.x,qv.x,a); a = fmaf(tv.y,qv.y,a);
            a = fmaf(tv.z,qv.z,a); a = fmaf(tv.w,qv.w,a);
          }
          a += __shfl_xor(a, 1); a += __shfl_xor(a, 2); a += __shfl_xor(a, 4);
          if (cc == 0) {
            float pv = expf(a);
            pL[rr] = pv;
            (ws + OFF_P)[(size_t)b*512u + tbase + ti*25 + rr] = pv;
          }
        }
        __syncthreads();
        if (tid < 32) {
          float pv = (tid < 25) ? pL[tid] : 0.f;
          pv += __shfl_xor(pv, 1); pv += __shfl_xor(pv, 2); pv += __shfl_xor(pv, 4);
          pv += __shfl_xor(pv, 8); pv += __shfl_xor(pv, 16);
          if (tid == 0) ltot += pv;
        }
        {
          const float* tb = tile + dqq;
          for (int r = rs; r < rs + rcnt; ++r) {
            float w = pL[r];
            float4 tv = *(const float4*)(tb + r*520);
            sa0 = fmaf(w, tv.x, sa0); sa1 = fmaf(w, tv.y, sa1);
            sa2 = fmaf(w, tv.z, sa2); sa3 = fmaf(w, tv.w, sa3);
          }
        }
        __syncthreads();
      }
      {
        float4 sv; sv.x = sa0; sv.y = sa1; sv.z = sa2; sv.w = sa3;
        *(float4*)(sred + qr*512 + dqq) = sv;
      }
      __syncthreads();
      if (tid < 128) {
        int d4 = tid*4;
        float4 s0 = *(float4*)(sred + d4);
        float4 s1 = *(float4*)(sred + 512 + d4);
        float4 s2 = *(float4*)(sred + 1024 + d4);
        float4 s3 = *(float4*)(sred + 1536 + d4);
        float4 sv;
        sv.x = s0.x+s1.x+s2.x+s3.x; sv.y = s0.y+s1.y+s2.y+s3.y;
        sv.z = s0.z+s1.z+s2.z+s3.z; sv.w = s0.w+s1.w+s2.w+s3.w;
        *(float4*)(ws + OFF_PS + (size_t)(b*2 + tau)*512u + d4) = sv;
      }
      if (tid == 0) (ws + OFF_PL)[b*2 + tau] = ltot;
    }
    gridbar(ws, ++bstep);

    // ========== Phase D : ctx combine + o2c + logits + outputs ==========
    {
      const int bt = blk >> 4, it = blk & 15;
      const int b0 = bt*8, i0 = it*32;
      float* xo   = smem;            // [8][1032]
      float* scsL = smem + 8256;     // 8
      float* hidP = smem + 8264;     // [2][256]
      float* hidL = smem + 8776;     // [8][33]
      if (tid < 8) {
        int bb = b0 + tid;
        scsL[tid] = 1.f / ((ws + OFF_PL)[bb*2] + (ws + OFF_PL)[bb*2 + 1]);
      }
      __syncthreads();
      for (int i = tid; i < 1024; i += NTHR) {
        int bl = i >> 7, kq = (i & 127)*4;
        float4 h = *(const float4*)(ws + OFF_H1BK + (size_t)(b0+bl)*512u + kq);
        *(float4*)(xo + bl*1032 + kq) = h;
      }
      for (int i = tid; i < 1024; i += NTHR) {
        int bl = i >> 7, dq2 = (i & 127)*4;
        const float* psd = ws + OFF_PS + (size_t)(b0 + bl)*2u*512u;
        float4 p0 = *(const float4*)(psd + dq2);
        float4 p1 = *(const float4*)(psd + 512 + dq2);
        float sc = scsL[bl];
        float4 v;
        v.x = (p0.x+p1.x)*sc; v.y = (p0.y+p1.y)*sc;
        v.z = (p0.z+p1.z)*sc; v.w = (p0.w+p1.w)*sc;
        *(float4*)(xo + bl*1032 + 512 + dq2) = v;
      }
      __syncthreads();
      {
        const int bl = tid & 7, il = (tid >> 3) & 31, kh = tid >> 8;
        float a = 0.f;
        const float4* Gr = (const float4*)(ws + OFF_GM + (size_t)(i0 + il)*1024u + kh*512);
        const float4* xr = (const float4*)(xo + bl*1032 + kh*512);
        for (int k2 = 0; k2 < 128; ++k2) {
          float4 g = Gr[k2], x = xr[k2];
          a = fmaf(g.x,x.x,a); a = fmaf(g.y,x.y,a);
          a = fmaf(g.z,x.z,a); a = fmaf(g.w,x.w,a);
        }
        hidP[(kh << 8) + (tid & 255)] = a;
      }
      __syncthreads();
      if (tid < 256) {
        int bl = tid & 7, il = tid >> 3;
        float h = hidP[tid] + hidP[256 + tid] + (ws + OFF_BG)[i0 + il];
        hidL[bl*33 + il] = fmaxf(h, 0.f);
      }
      if (it == 0) {
        for (int i = tid; i < 1000; i += NTHR) {
          int bl = i / 125, f = i - bl*125;
          int bb = b0 + bl;
          float4 pv = *(const float4*)((ws + OFF_P) + (size_t)bb*512u + f*4);
          float sc = scsL[bl];
          f32x4 v = { pv.x*sc, pv.y*sc, pv.z*sc, pv.w*sc };
          __builtin_nontemporal_store(v,
              (f32x4*)(attnout + ((size_t)bb*TDEC + t)*TENC + f*4));
        }
        for (int i = tid; i < 4096; i += NTHR) {
          int bl = i & 7, d = i >> 3;
          (ws + OFF_ST)[(size_t)d*128 + b0 + bl] = xo[bl*1032 + 512 + d];
        }
      }
      __syncthreads();
      if (tid < 248) {
        int bl = tid & 7, v = tid >> 3;
        float s = 0.f;
        const float* er = emb + (size_t)v*512u + i0;
        const float* hb = hidL + bl*33;
        #pragma unroll
        for (int ii = 0; ii < 32; ++ii) s = fmaf(hb[ii], er[ii], s);
        float* Lw = ws + OFF_LB + (size_t)p*4096u;
        atomicAdd(&Lw[(b0 + bl)*32 + v], s);
      }
    }
    gridbar(ws, ++bstep);
  } // t loop

  // final logits row (t = 549, parity 1)
  if (blk < 16) {
    const float* Lb = ws + OFF_LB + 4096u;
    for (int i = tid; i < 248; i += NTHR) {
      int bl = i / 31, v = i - bl*31;
      int bb = blk*8 + bl;
      __builtin_nontemporal_store(Lb[bb*32 + v] + bcp[v],
          rawout + ((size_t)bb*TDEC + (TDEC-1))*VOC + v);
    }
  }
}

// ---------------- launch ----------------
extern "C" void kernel_launch(void* const* d_in, const int* in_sizes, int n_in,
                              void* d_out, int out_size, void* d_ws, size_t ws_size,
                              hipStream_t stream)
{
  (void)in_sizes; (void)n_in; (void)out_size; (void)ws_size;
  const float* enc   = (const float*)d_in[0];
  const float* emb   = (const float*)d_in[1];
  const float* w_ih0 = (const float*)d_in[2];
  const float* w_hh0 = (const float*)d_in[3];
  const float* b_ih0 = (const float*)d_in[4];
  const float* b_hh0 = (const float*)d_in[5];
  const float* w_ih1 = (const float*)d_in[6];
  const float* w_hh1 = (const float*)d_in[7];
  const float* b_ih1 = (const float*)d_in[8];
  const float* b_hh1 = (const float*)d_in[9];
  const float* wk    = (const float*)d_in[10];
  const float* wvm   = (const float*)d_in[11];
  const float* w_o2c = (const float*)d_in[12];
  const float* b_o2c = (const float*)d_in[13];
  const float* bcp   = (const float*)d_in[14];
  float* ws   = (float*)d_ws;
  float* outp = (float*)d_out;

  initCopy<<<2048, 256, 0, stream>>>(w_hh0, w_ih1, w_hh1, w_o2c,
                                     b_ih0, b_hh0, b_ih1, b_hh1, b_o2c, wk, ws);
  initGemm<<<2048, 256, 0, stream>>>(w_ih0, w_o2c, wvm, emb, ws);
  speller_main<<<NBLK, NTHR, 0, stream>>>(enc, emb, wk, bcp, ws, outp);
}

// Round 5
// 96875.391 us; speedup vs baseline: 1.9042x; 1.9042x over previous
//
#include <hip/hip_runtime.h>
#include <math.h>

#define BATCH 128
#define TDEC  550
#define TENC  500
#define EDIM  512
#define VOC   31
#define NBLK  256
#define NTHR  512

// ---------------- workspace layout (float offsets) ----------------
#define OFF_WA   0u                          // [2048][1024] cols 0..511 = M (s-part), 512..1023 = w_hh0
#define OFF_WB   (OFF_WA + 2097152u)         // [2048][1024] cols 0..511 = w_ih1, 512..1023 = w_hh1
#define OFF_GM   (OFF_WB + 2097152u)         // [512][1024]  cols 0..511 = w_o2c[:, :512], 512.. = M2
#define OFF_E2G  (OFF_GM + 524288u)          // [31][2048]
#define OFF_BA   (OFF_E2G + 63488u)          // [2048]
#define OFF_BB   (OFF_BA + 2048u)            // [2048]
#define OFF_BG   (OFF_BB + 2048u)            // [512]
#define OFF_ST   (OFF_BG + 512u)             // s~ [512][128]
#define OFF_H0T0 (OFF_ST   + 65536u)
#define OFF_H0T1 (OFF_H0T0 + 65536u)
#define OFF_H1T0 (OFF_H0T1 + 65536u)
#define OFF_H1T1 (OFF_H1T0 + 65536u)
#define OFF_C0T  (OFF_H1T1 + 65536u)
#define OFF_C1T  (OFF_C0T  + 65536u)
#define OFF_P    (OFF_C1T  + 65536u)         // exp(e) [128][512] (500 used)
#define OFF_PL   (OFF_P    + 65536u)         // l partials [128][2]
#define OFF_PS   (OFF_PL   + 256u)           // s partials [128][2][512]
#define OFF_LB   (OFF_PS   + 131072u)        // logits dbl-buf [2][128][32]
#define OFF_BAR  (OFF_LB   + 8192u)          // barrier: 256 flag cells (16 u32 apart) + gen @4096; 8192 u32
#define OFF_WKT  (OFF_BAR  + 8192u)          // wkT [512 e][512 d]
#define OFF_H1BK (OFF_WKT  + 262144u)        // h1 in [b][k] layout [128][512]

// ---------------- init kernel 1: copies / biases / zeros / wkT ----------------
__global__ void initCopy(const float* __restrict__ w_hh0, const float* __restrict__ w_ih1,
                         const float* __restrict__ w_hh1, const float* __restrict__ w_o2c,
                         const float* __restrict__ b_ih0, const float* __restrict__ b_hh0,
                         const float* __restrict__ b_ih1, const float* __restrict__ b_hh1,
                         const float* __restrict__ b_o2c, const float* __restrict__ wk,
                         float* __restrict__ ws)
{
  const unsigned n0 = 2048u*512u;      // WA right (w_hh0)
  const unsigned n1 = 2048u*512u;      // WB left  (w_ih1)
  const unsigned n2 = 2048u*512u;      // WB right (w_hh1)
  const unsigned n3 = 512u*512u;       // GM left
  const unsigned nz = 7u*65536u;       // ST,H0T0,H0T1,H1T0,H1T1,C0T,C1T
  const unsigned nw = 262144u;         // wkT
  const unsigned NT = n0+n1+n2+n3 + 2048u+2048u+512u + nz + 8192u + 8192u + nw;
  for (unsigned i = blockIdx.x*blockDim.x + threadIdx.x; i < NT; i += gridDim.x*blockDim.x) {
    unsigned j = i;
    if (j < n0) { unsigned r = j>>9, k = j&511u;
      ws[OFF_WA + r*1024u + 512u + k] = w_hh0[j]; continue; }
    j -= n0;
    if (j < n1) { unsigned r = j>>9, k = j&511u;
      ws[OFF_WB + r*1024u + k] = w_ih1[j]; continue; }
    j -= n1;
    if (j < n2) { unsigned r = j>>9, k = j&511u;
      ws[OFF_WB + r*1024u + 512u + k] = w_hh1[j]; continue; }
    j -= n2;
    if (j < n3) { unsigned r = j>>9, k = j&511u;
      ws[OFF_GM + r*1024u + k] = w_o2c[r*1024u + k]; continue; }
    j -= n3;
    if (j < 2048u) { ws[OFF_BA + j] = b_ih0[j] + b_hh0[j]; continue; }
    j -= 2048u;
    if (j < 2048u) { ws[OFF_BB + j] = b_ih1[j] + b_hh1[j]; continue; }
    j -= 2048u;
    if (j < 512u)  { ws[OFF_BG + j] = b_o2c[j]; continue; }
    j -= 512u;
    if (j < nz)    { ws[OFF_ST + j] = 0.f; continue; }
    j -= nz;
    if (j < 8192u) {
      unsigned buf = j>>12, v = j & 31u;
      ws[OFF_LB + j] = (buf==1u && v==0u) ? 1e9f : 0.f;   // argmax -> SOS(=0) at t=0
      continue; }
    j -= 8192u;
    if (j < 8192u) { ((unsigned*)(ws + OFF_BAR))[j] = 0u; continue; }
    j -= 8192u;
    { unsigned e = j>>9, d = j&511u;
      ws[OFF_WKT + j] = wk[d*512u + e]; }
  }
}

// ---------------- init kernel 2: folded weight GEMMs ----------------
__global__ void initGemm(const float* __restrict__ w_ih0, const float* __restrict__ w_o2c,
                         const float* __restrict__ wvm, const float* __restrict__ emb,
                         float* __restrict__ ws)
{
  const unsigned n0 = 2048u*512u;   // M  -> WA left
  const unsigned n1 = 512u*512u;    // M2 -> GM right
  const unsigned n2 = 31u*2048u;    // E2G
  const unsigned NT = n0+n1+n2;
  for (unsigned i = blockIdx.x*blockDim.x + threadIdx.x; i < NT; i += gridDim.x*blockDim.x) {
    if (i < n0) {
      unsigned r = i>>9, d = i&511u;
      const float* a = w_ih0 + (size_t)r*1024u + 512u;
      const float* b = wvm + (size_t)d*512u;
      float s = 0.f;
      for (int k = 0; k < 512; ++k) s = fmaf(a[k], b[k], s);
      ws[OFF_WA + r*1024u + d] = s;
    } else if (i < n0+n1) {
      unsigned j = i - n0; unsigned r = j>>9, d = j&511u;
      const float* a = w_o2c + (size_t)r*1024u + 512u;
      const float* b = wvm + (size_t)d*512u;
      float s = 0.f;
      for (int k = 0; k < 512; ++k) s = fmaf(a[k], b[k], s);
      ws[OFF_GM + r*1024u + 512u + d] = s;
    } else {
      unsigned j = i - n0 - n1; unsigned v = j>>11, g = j&2047u;
      const float* a = emb + (size_t)v*512u;
      const float* b = w_ih0 + (size_t)g*1024u;
      float s = 0.f;
      for (int k = 0; k < 512; ++k) s = fmaf(a[k], b[k], s);
      ws[OFF_E2G + v*2048u + g] = s;
    }
  }
}

// ---------------- flag-array grid barrier (no atomic chains) ----------------
// flags[blk] at BAR + blk*16 (one 64B line each); gen at BAR + 4096.
// Block 0 aggregates: threads 1..255 poll flags in parallel, then release gen.
__device__ __forceinline__ void gridbar(float* ws, unsigned tgt)
{
  unsigned* base = (unsigned*)(ws + OFF_BAR);
  __syncthreads();
  if (blockIdx.x == 0) {
    const int tid = threadIdx.x;
    if (tid > 0 && tid < 256) {
      unsigned* f = base + tid*16;
      while (__hip_atomic_load(f, __ATOMIC_RELAXED, __HIP_MEMORY_SCOPE_AGENT) < tgt)
        __builtin_amdgcn_s_sleep(4);
    }
    __syncthreads();
    if (tid == 0) {
      __builtin_amdgcn_fence(__ATOMIC_ACQUIRE, "agent");
      __hip_atomic_store(base + 4096, tgt, __ATOMIC_RELEASE, __HIP_MEMORY_SCOPE_AGENT);
    }
    __syncthreads();
  } else {
    if (threadIdx.x == 0) {
      __hip_atomic_store(base + blockIdx.x*16, tgt, __ATOMIC_RELEASE, __HIP_MEMORY_SCOPE_AGENT);
      while (__hip_atomic_load(base + 4096, __ATOMIC_RELAXED, __HIP_MEMORY_SCOPE_AGENT) < tgt)
        __builtin_amdgcn_s_sleep(8);
      __builtin_amdgcn_fence(__ATOMIC_ACQUIRE, "agent");
    }
    __syncthreads();
  }
}

__device__ __forceinline__ float sigm(float x) { return 1.f/(1.f + expf(-x)); }

// ---------------- main persistent kernel ----------------
__launch_bounds__(NTHR)
__global__ void speller_main(const float* __restrict__ enc, const float* __restrict__ emb,
                             const float* __restrict__ wk,  const float* __restrict__ bcp,
                             float* __restrict__ ws, float* __restrict__ out)
{
  __shared__ __align__(16) float smem[15616];
  __shared__ int symL[128];
  const int tid = threadIdx.x;
  const int blk = blockIdx.x;
  unsigned bstep = 0;

  float* rawout  = out;                                   // [128][550][31]
  float* attnout = out + (size_t)BATCH*TDEC*VOC;          // [128][550][500]

  for (int t = 0; t < TDEC; ++t) {
    const int p = t & 1;
    float*       h0_cur  = ws + (p ? OFF_H0T1 : OFF_H0T0);
    const float* h0_prev = ws + (p ? OFF_H0T0 : OFF_H0T1);
    float*       h1_cur  = ws + (p ? OFF_H1T1 : OFF_H1T0);
    const float* h1_prev = ws + (p ? OFF_H1T0 : OFF_H1T1);

    // ========== Phase A : argmax feedback + LSTM0 (block owns j0=blk*2) ==========
    {
      const float* Lb = ws + OFF_LB + (size_t)(p^1)*4096u;
      if (blk < 16) {
        if (t > 0) {
          for (int i = tid; i < 248; i += NTHR) {
            int bl = i / 31, v = i - bl*31;
            int bb = blk*8 + bl;
            rawout[((size_t)bb*TDEC + (t-1))*VOC + v] = Lb[bb*32 + v] + bcp[v];
          }
        }
      } else if (blk == 16) {
        float* Lz = ws + OFF_LB + (size_t)p*4096u;
        for (int i = tid; i < 4096; i += NTHR) Lz[i] = 0.f;
      }
      if (tid < 128) {
        float best = -3.4e38f; int sy = 0;
        for (int v = 0; v < VOC; ++v) {
          float f = Lb[tid*32 + v] + bcp[v];
          if (f > best) { best = f; sy = v; }
        }
        symL[tid] = sy;
      }
      const int b  = tid & 127;
      const int kg = tid >> 7;
      const int j0 = blk*2;
      const float* xb = ((kg < 2) ? (ws + OFF_ST + (size_t)kg*256u*128u)
                                  : (h0_prev + (size_t)(kg-2)*256u*128u)) + b;
      const float* wr[8];
      #pragma unroll
      for (int r = 0; r < 8; ++r) {
        int gi = r >> 1, jl = r & 1;
        wr[r] = ws + OFF_WA + (size_t)(gi*512 + j0 + jl)*1024u + kg*256;
      }
      float acc[8] = {0,0,0,0,0,0,0,0};
      for (int k = 0; k < 256; ++k) {
        float xv = xb[(size_t)k*128u];
        #pragma unroll
        for (int r = 0; r < 8; ++r) acc[r] = fmaf(xv, wr[r][k], acc[r]);
      }
      float* lacc = smem;
      __syncthreads();
      #pragma unroll
      for (int r = 0; r < 8; ++r) lacc[(kg*128 + b)*9 + r] = acc[r];
      __syncthreads();
      if (tid < 256) {
        const int bb = tid & 127, jl = tid >> 7;
        const int j = j0 + jl;
        float gv[4];
        #pragma unroll
        for (int gi = 0; gi < 4; ++gi) {
          float s = 0.f;
          #pragma unroll
          for (int kg2 = 0; kg2 < 4; ++kg2) s += lacc[(kg2*128 + bb)*9 + gi*2 + jl];
          s += (ws + OFF_E2G)[(size_t)symL[bb]*2048u + gi*512 + j];
          s += (ws + OFF_BA)[gi*512 + j];
          gv[gi] = s;
        }
        float ig = sigm(gv[0]), fg = sigm(gv[1]);
        float gg = tanhf(gv[2]), og = sigm(gv[3]);
        float cold = (ws + OFF_C0T)[(size_t)j*128 + bb];
        float cnew = fg*cold + ig*gg;
        (ws + OFF_C0T)[(size_t)j*128 + bb] = cnew;
        h0_cur[(size_t)j*128 + bb] = og*tanhf(cnew);
      }
    }
    gridbar(ws, ++bstep);

    // ========== Phase B : LSTM1 (also writes h1bk transposed copy) ==========
    {
      const int b  = tid & 127;
      const int kg = tid >> 7;
      const int j0 = blk*2;
      const float* xb = ((kg < 2) ? (h0_cur + (size_t)kg*256u*128u)
                                  : (h1_prev + (size_t)(kg-2)*256u*128u)) + b;
      const float* wr[8];
      #pragma unroll
      for (int r = 0; r < 8; ++r) {
        int gi = r >> 1, jl = r & 1;
        wr[r] = ws + OFF_WB + (size_t)(gi*512 + j0 + jl)*1024u + kg*256;
      }
      float acc[8] = {0,0,0,0,0,0,0,0};
      for (int k = 0; k < 256; ++k) {
        float xv = xb[(size_t)k*128u];
        #pragma unroll
        for (int r = 0; r < 8; ++r) acc[r] = fmaf(xv, wr[r][k], acc[r]);
      }
      float* lacc = smem;
      __syncthreads();
      #pragma unroll
      for (int r = 0; r < 8; ++r) lacc[(kg*128 + b)*9 + r] = acc[r];
      __syncthreads();
      if (tid < 256) {
        const int bb = tid & 127, jl = tid >> 7;
        const int j = j0 + jl;
        float gv[4];
        #pragma unroll
        for (int gi = 0; gi < 4; ++gi) {
          float s = 0.f;
          #pragma unroll
          for (int kg2 = 0; kg2 < 4; ++kg2) s += lacc[(kg2*128 + bb)*9 + gi*2 + jl];
          s += (ws + OFF_BB)[gi*512 + j];
          gv[gi] = s;
        }
        float ig = sigm(gv[0]), fg = sigm(gv[1]);
        float gg = tanhf(gv[2]), og = sigm(gv[3]);
        float cold = (ws + OFF_C1T)[(size_t)j*128 + bb];
        float cnew = fg*cold + ig*gg;
        (ws + OFF_C1T)[(size_t)j*128 + bb] = cnew;
        float hval = og*tanhf(cnew);
        h1_cur[(size_t)j*128 + bb] = hval;
        (ws + OFF_H1BK)[(size_t)bb*512u + j] = hval;   // transposed copy for C/D
      }
    }
    gridbar(ws, ++bstep);

    // ========== Phase C : q + pipelined attention (block=(b,tau)) ==========
    {
      const int b = blk >> 1, tau = blk & 1;
      const int tbase = tau*250;
      float* tile = smem;            // [25][520] = 13000
      float* qL   = smem + 13000;    // 512
      float* pL   = smem + 13520;    // 32
      float* sred = smem + 13568;    // [4][512]
      float* h1L  = sred;            // alias (used before sred)

      if (tid < 128) {
        float4 h = *(const float4*)(ws + OFF_H1BK + (size_t)b*512u + tid*4);
        *(float4*)(h1L + tid*4) = h;
      }
      __syncthreads();
      // q[d] = sum_e wkT[e][d]*h1[e], 4-way e-split
      {
        const int eg = tid >> 7, dqq = (tid & 127)*4;
        const int e0 = eg*128;
        float4 qa = {0.f,0.f,0.f,0.f};
        const float* wkt = ws + OFF_WKT;
        for (int e = 0; e < 128; ++e) {
          float hv = h1L[e0 + e];
          float4 wv4 = *(const float4*)(wkt + (size_t)(e0+e)*512u + dqq);
          qa.x = fmaf(hv, wv4.x, qa.x); qa.y = fmaf(hv, wv4.y, qa.y);
          qa.z = fmaf(hv, wv4.z, qa.z); qa.w = fmaf(hv, wv4.w, qa.w);
        }
        *(float4*)(tile + eg*512 + dqq) = qa;   // tile as scratch
      }
      __syncthreads();
      if (tid < 128) {
        int dqq = tid*4;
        float4 a0 = *(float4*)(tile + dqq);
        float4 a1 = *(float4*)(tile + 512 + dqq);
        float4 a2 = *(float4*)(tile + 1024 + dqq);
        float4 a3 = *(float4*)(tile + 1536 + dqq);
        float4 q4;
        q4.x = a0.x+a1.x+a2.x+a3.x; q4.y = a0.y+a1.y+a2.y+a3.y;
        q4.z = a0.z+a1.z+a2.z+a3.z; q4.w = a0.w+a1.w+a2.w+a3.w;
        *(float4*)(qL + dqq) = q4;
      }
      // prologue: prefetch tile 0
      float4 rv[7];
      const float* encb = enc + ((size_t)b*TENC + tbase)*EDIM;
      #pragma unroll
      for (int jj = 0; jj < 7; ++jj) {
        int i2 = tid + jj*512;
        if (i2 < 3200) rv[jj] = *(const float4*)(encb + (size_t)i2*4u);
      }
      float sa0=0.f, sa1=0.f, sa2=0.f, sa3=0.f;
      float ltot = 0.f;
      const int rr = tid >> 3, cc = tid & 7;
      const int qr = tid >> 7, dqq = (tid & 127)*4;
      const int rs = qr*6 + (qr>0 ? 1 : 0);
      const int rcnt = (qr==0) ? 7 : 6;
      __syncthreads();   // qL ready, tile scratch free
      for (int ti = 0; ti < 10; ++ti) {
        #pragma unroll
        for (int jj = 0; jj < 7; ++jj) {
          int i2 = tid + jj*512;
          if (i2 < 3200) { int r = i2 >> 7, c = i2 & 127; *(float4*)(tile + r*520 + c*4) = rv[jj]; }
        }
        __syncthreads();
        if (ti < 9) {      // prefetch next tile (overlaps compute)
          const float* encn = encb + (size_t)(ti+1)*25u*EDIM;
          #pragma unroll
          for (int jj = 0; jj < 7; ++jj) {
            int i2 = tid + jj*512;
            if (i2 < 3200) rv[jj] = *(const float4*)(encn + (size_t)i2*4u);
          }
        }
        if (rr < 25) {
          float a = 0.f;
          const float* tr = tile + rr*520;
          #pragma unroll
          for (int i = 0; i < 16; ++i) {
            int d = i*32 + cc*4;
            float4 tv = *(const float4*)(tr + d);
            float4 qv = *(const float4*)(qL + d);
            a = fmaf(tv.x,qv.x,a); a = fmaf(tv.y,qv.y,a);
            a = fmaf(tv.z,qv.z,a); a = fmaf(tv.w,qv.w,a);
          }
          a += __shfl_xor(a, 1); a += __shfl_xor(a, 2); a += __shfl_xor(a, 4);
          if (cc == 0) {
            float pv = expf(a);
            pL[rr] = pv;
            (ws + OFF_P)[(size_t)b*512u + tbase + ti*25 + rr] = pv;
          }
        }
        __syncthreads();
        if (tid < 32) {
          float pv = (tid < 25) ? pL[tid] : 0.f;
          pv += __shfl_xor(pv, 1); pv += __shfl_xor(pv, 2); pv += __shfl_xor(pv, 4);
          pv += __shfl_xor(pv, 8); pv += __shfl_xor(pv, 16);
          if (tid == 0) ltot += pv;
        }
        {
          const float* tb = tile + dqq;
          for (int r = rs; r < rs + rcnt; ++r) {
            float w = pL[r];
            float4 tv = *(const float4*)(tb + r*520);
            sa0 = fmaf(w, tv.x, sa0); sa1 = fmaf(w, tv.y, sa1);
            sa2 = fmaf(w, tv.z, sa2); sa3 = fmaf(w, tv.w, sa3);
          }
        }
        __syncthreads();
      }
      {
        float4 sv; sv.x = sa0; sv.y = sa1; sv.z = sa2; sv.w = sa3;
        *(float4*)(sred + qr*512 + dqq) = sv;
      }
      __syncthreads();
      if (tid < 128) {
        int d4 = tid*4;
        float4 s0 = *(float4*)(sred + d4);
        float4 s1 = *(float4*)(sred + 512 + d4);
        float4 s2 = *(float4*)(sred + 1024 + d4);
        float4 s3 = *(float4*)(sred + 1536 + d4);
        float4 sv;
        sv.x = s0.x+s1.x+s2.x+s3.x; sv.y = s0.y+s1.y+s2.y+s3.y;
        sv.z = s0.z+s1.z+s2.z+s3.z; sv.w = s0.w+s1.w+s2.w+s3.w;
        *(float4*)(ws + OFF_PS + (size_t)(b*2 + tau)*512u + d4) = sv;
      }
      if (tid == 0) (ws + OFF_PL)[b*2 + tau] = ltot;
    }
    gridbar(ws, ++bstep);

    // ========== Phase D : ctx combine + o2c + logits + outputs ==========
    {
      const int bt = blk >> 4, it = blk & 15;
      const int b0 = bt*8, i0 = it*32;
      float* xo   = smem;            // [8][1032]
      float* scsL = smem + 8256;     // 8
      float* hidP = smem + 8264;     // [2][256]
      float* hidL = smem + 8776;     // [8][33]
      if (tid < 8) {
        int bb = b0 + tid;
        scsL[tid] = 1.f / ((ws + OFF_PL)[bb*2] + (ws + OFF_PL)[bb*2 + 1]);
      }
      __syncthreads();
      for (int i = tid; i < 1024; i += NTHR) {
        int bl = i >> 7, kq = (i & 127)*4;
        float4 h = *(const float4*)(ws + OFF_H1BK + (size_t)(b0+bl)*512u + kq);
        *(float4*)(xo + bl*1032 + kq) = h;
      }
      for (int i = tid; i < 1024; i += NTHR) {
        int bl = i >> 7, dq2 = (i & 127)*4;
        const float* psd = ws + OFF_PS + (size_t)(b0 + bl)*2u*512u;
        float4 p0 = *(const float4*)(psd + dq2);
        float4 p1 = *(const float4*)(psd + 512 + dq2);
        float sc = scsL[bl];
        float4 v;
        v.x = (p0.x+p1.x)*sc; v.y = (p0.y+p1.y)*sc;
        v.z = (p0.z+p1.z)*sc; v.w = (p0.w+p1.w)*sc;
        *(float4*)(xo + bl*1032 + 512 + dq2) = v;
      }
      __syncthreads();
      {
        const int bl = tid & 7, il = (tid >> 3) & 31, kh = tid >> 8;
        float a = 0.f;
        const float4* Gr = (const float4*)(ws + OFF_GM + (size_t)(i0 + il)*1024u + kh*512);
        const float4* xr = (const float4*)(xo + bl*1032 + kh*512);
        for (int k2 = 0; k2 < 128; ++k2) {
          float4 g = Gr[k2], x = xr[k2];
          a = fmaf(g.x,x.x,a); a = fmaf(g.y,x.y,a);
          a = fmaf(g.z,x.z,a); a = fmaf(g.w,x.w,a);
        }
        hidP[(kh << 8) + (tid & 255)] = a;
      }
      __syncthreads();
      if (tid < 256) {
        int bl = tid & 7, il = tid >> 3;
        float h = hidP[tid] + hidP[256 + tid] + (ws + OFF_BG)[i0 + il];
        hidL[bl*33 + il] = fmaxf(h, 0.f);
      }
      if (it == 0) {
        for (int i = tid; i < 1000; i += NTHR) {
          int bl = i / 125, f = i - bl*125;
          int bb = b0 + bl;
          float4 pv = *(const float4*)((ws + OFF_P) + (size_t)bb*512u + f*4);
          float sc = scsL[bl];
          float4 v; v.x = pv.x*sc; v.y = pv.y*sc; v.z = pv.z*sc; v.w = pv.w*sc;
          *(float4*)(attnout + ((size_t)bb*TDEC + t)*TENC + f*4) = v;
        }
        for (int i = tid; i < 4096; i += NTHR) {
          int bl = i & 7, d = i >> 3;
          (ws + OFF_ST)[(size_t)d*128 + b0 + bl] = xo[bl*1032 + 512 + d];
        }
      }
      __syncthreads();
      if (tid < 248) {
        int bl = tid & 7, v = tid >> 3;
        float s = 0.f;
        const float* er = emb + (size_t)v*512u + i0;
        const float* hb = hidL + bl*33;
        #pragma unroll
        for (int ii = 0; ii < 32; ++ii) s = fmaf(hb[ii], er[ii], s);
        float* Lw = ws + OFF_LB + (size_t)p*4096u;
        atomicAdd(&Lw[(b0 + bl)*32 + v], s);
      }
    }
    gridbar(ws, ++bstep);
  } // t loop

  // final logits row (t = 549, parity 1)
  if (blk < 16) {
    const float* Lb = ws + OFF_LB + 4096u;
    for (int i = tid; i < 248; i += NTHR) {
      int bl = i / 31, v = i - bl*31;
      int bb = blk*8 + bl;
      rawout[((size_t)bb*TDEC + (TDEC-1))*VOC + v] = Lb[bb*32 + v] + bcp[v];
    }
  }
}

// ---------------- launch ----------------
extern "C" void kernel_launch(void* const* d_in, const int* in_sizes, int n_in,
                              void* d_out, int out_size, void* d_ws, size_t ws_size,
                              hipStream_t stream)
{
  (void)in_sizes; (void)n_in; (void)out_size; (void)ws_size;
  const float* enc   = (const float*)d_in[0];
  const float* emb   = (const float*)d_in[1];
  const float* w_ih0 = (const float*)d_in[2];
  const float* w_hh0 = (const float*)d_in[3];
  const float* b_ih0 = (const float*)d_in[4];
  const float* b_hh0 = (const float*)d_in[5];
  const float* w_ih1 = (const float*)d_in[6];
  const float* w_hh1 = (const float*)d_in[7];
  const float* b_ih1 = (const float*)d_in[8];
  const float* b_hh1 = (const float*)d_in[9];
  const float* wk    = (const float*)d_in[10];
  const float* wvm   = (const float*)d_in[11];
  const float* w_o2c = (const float*)d_in[12];
  const float* b_o2c = (const float*)d_in[13];
  const float* bcp   = (const float*)d_in[14];
  float* ws   = (float*)d_ws;
  float* outp = (float*)d_out;

  initCopy<<<2048, 256, 0, stream>>>(w_hh0, w_ih1, w_hh1, w_o2c,
                                     b_ih0, b_hh0, b_ih1, b_hh1, b_o2c, wk, ws);
  initGemm<<<2048, 256, 0, stream>>>(w_ih0, w_o2c, wvm, emb, ws);
  speller_main<<<NBLK, NTHR, 0, stream>>>(enc, emb, wk, bcp, ws, outp);
}